// Round 9
// baseline (195.830 us; speedup 1.0000x reference)
//
#include <hip/hip_runtime.h>
#include <math.h>

#define NC 4096
#define OVCAP 131072
#define CAP1 8520      // per (bucket,xcd) sub-bin: mean 7813 + 8 sigma

// Real XCD id: s_getreg(HW_REG_XCC_ID=20, offset 0, size 4) [verified r6]
__device__ __forceinline__ int xcd_id() {
    return (int)__builtin_amdgcn_s_getreg(20 | (0 << 6) | ((4 - 1) << 11));
}

// ---------------- shared per-cluster eigensolve --------------------------------
__device__ __forceinline__ void solve_cluster(const float mom[10], float* o,
                                              float4* pcv, float4* pvv) {
    float cntf = mom[0];
    double dn  = (double)cntf;
    double inv = 1.0 / fmax(dn, 1.0);
    double cx = mom[1] * inv, cy = mom[2] * inv, cz = mom[3] * inv;

    double a00 = (double)mom[4] - dn * cx * cx;
    double a01 = (double)mom[5] - dn * cx * cy;
    double a02 = (double)mom[6] - dn * cx * cz;
    double a11 = (double)mom[7] - dn * cy * cy;
    double a12 = (double)mom[8] - dn * cy * cz;
    double a22 = (double)mom[9] - dn * cz * cz;

    double q  = (a00 + a11 + a22) / 3.0;
    double p1 = a01 * a01 + a02 * a02 + a12 * a12;
    double b00 = a00 - q, b11 = a11 - q, b22 = a22 - q;
    double p2 = b00 * b00 + b11 * b11 + b22 * b22 + 2.0 * p1;
    double w0, w1, w2;
    if (!(p2 > 0.0)) {
        w0 = w1 = w2 = q;
    } else {
        double p  = sqrt(p2 / 6.0);
        double ip = 1.0 / p;
        double c00 = b00 * ip, c01 = a01 * ip, c02 = a02 * ip;
        double c11 = b11 * ip, c12 = a12 * ip, c22 = b22 * ip;
        double detB = c00 * (c11 * c22 - c12 * c12)
                    - c01 * (c01 * c22 - c12 * c02)
                    + c02 * (c01 * c12 - c11 * c02);
        double r = fmin(1.0, fmax(-1.0, detB * 0.5));
        double phi = acos(r) / 3.0;
        w2 = q + 2.0 * p * cos(phi);
        w0 = q + 2.0 * p * cos(phi + 2.0943951023931953);
        w1 = 3.0 * q - w2 - w0;
    }

    double denom = (w2 == 0.0) ? 1.0 : w2;
    double dirwt = (w2 == 0.0) ? 0.0 : (1.0 - w1 / w2);

    double C00 = a00 - w1, C11 = a11 - w1, C22 = a22 - w1;
    double D00 = a00 - w0, D11 = a11 - w0, D22 = a22 - w0;
    double M00 = C00 * D00 + a01 * a01 + a02 * a02;
    double M10 = a01 * D00 + C11 * a01 + a12 * a02;
    double M20 = a02 * D00 + a12 * a01 + C22 * a02;
    double M01 = C00 * a01 + a01 * D11 + a02 * a12;
    double M11 = a01 * a01 + C11 * D11 + a12 * a12;
    double M21 = a02 * a01 + a12 * D11 + C22 * a12;
    double M02 = C00 * a02 + a01 * a12 + a02 * D22;
    double M12 = a01 * a02 + C11 * a12 + a12 * D22;
    double M22 = a02 * a02 + a12 * a12 + C22 * D22;
    double n0 = M00 * M00 + M10 * M10 + M20 * M20;
    double n1 = M01 * M01 + M11 * M11 + M21 * M21;
    double n2 = M02 * M02 + M12 * M12 + M22 * M22;
    double vx, vy, vz, nn;
    if (n0 >= n1 && n0 >= n2) { vx = M00; vy = M10; vz = M20; nn = n0; }
    else if (n1 >= n2)        { vx = M01; vy = M11; vz = M21; nn = n1; }
    else                      { vx = M02; vy = M12; vz = M22; nn = n2; }
    if (nn > 1e-300) {
        double rn = 1.0 / sqrt(nn);
        vx *= rn; vy *= rn; vz *= rn;
    } else {
        vx = vy = vz = 0.0;
    }

    bool small = cntf < 2.0f;
    float bscale = small ? 0.0f : (float)(1.0 / denom);

    o[0]  = (float)cx;
    o[1]  = (float)cy;
    o[2]  = (float)cz;
    o[3]  = (float)a00 * bscale;
    o[4]  = (float)a01 * bscale;
    o[5]  = (float)a02 * bscale;
    o[6]  = (float)a01 * bscale;
    o[7]  = (float)a11 * bscale;
    o[8]  = (float)a12 * bscale;
    o[9]  = (float)a02 * bscale;
    o[10] = (float)a12 * bscale;
    o[11] = (float)a22 * bscale;
    o[15] = cntf;

    *pcv = make_float4((float)cx, (float)cy, (float)cz, (float)dirwt);
    *pvv = make_float4((float)vx, (float)vy, (float)vz, cntf);
}

__device__ __forceinline__ void ov_spill(float4 d, int id, float4* ov, int* novf,
                                         float* gmom) {
    int ovi = atomicAdd(novf, 1);
    if (ovi < OVCAP) ov[ovi] = d;
    atomicAdd(&gmom[0 * NC + id], 1.0f);
    atomicAdd(&gmom[1 * NC + id], d.x);
    atomicAdd(&gmom[2 * NC + id], d.y);
    atomicAdd(&gmom[3 * NC + id], d.z);
    atomicAdd(&gmom[4 * NC + id], d.x * d.x);
    atomicAdd(&gmom[5 * NC + id], d.x * d.y);
    atomicAdd(&gmom[6 * NC + id], d.x * d.z);
    atomicAdd(&gmom[7 * NC + id], d.y * d.y);
    atomicAdd(&gmom[8 * NC + id], d.y * d.z);
    atomicAdd(&gmom[9 * NC + id], d.z * d.z);
}

// ============================ FAST PATH ==========================================
// k_p1: radix pass 1 — voxels -> 64 buckets x 8 XCD shards. SoA P1 (x/y/z float
// + ushort id = 14 B/elem vs 16) cuts L3 traffic on all three P1 passes.
__global__ __launch_bounds__(512) void k_p1(const float* __restrict__ data,
                                            const int* __restrict__ ids,
                                            float* __restrict__ P1x,
                                            float* __restrict__ P1y,
                                            float* __restrict__ P1z,
                                            unsigned short* __restrict__ P1id,
                                            int* __restrict__ cnt1,
                                            float4* __restrict__ ov,
                                            int* __restrict__ novf,
                                            float* __restrict__ gmom, int n) {
    __shared__ float sbuf[6144];          // sx[2048] | sy[2048] | sz[2048]
    __shared__ unsigned short sid[2048];
    __shared__ int h64[64], boff[64], bglob[64];
    float* sx = sbuf;
    float* sy = sbuf + 2048;
    float* sz = sbuf + 4096;
    int tid = threadIdx.x, lane = tid & 63;
    int xcd = xcd_id() & 7;
    int ntiles = (n + 2047) >> 11;
    for (int t = blockIdx.x; t < ntiles; t += gridDim.x) {
        int vbase = t << 11;
        if (tid < 64) h64[tid] = 0;
        __syncthreads();
        float vx[4], vy[4], vz[4];
        int vid[4], vrk[4];
#pragma unroll
        for (int s = 0; s < 4; s++) {
            int v = vbase + (s << 9) + tid;
            if (v < n) {
                vx[s] = data[v * 5 + 0];
                vy[s] = data[v * 5 + 1];
                vz[s] = data[v * 5 + 2];
                int id = ids[v];
                vid[s] = id;
                vrk[s] = atomicAdd(&h64[id >> 6], 1);
            } else vid[s] = -1;
        }
        __syncthreads();
        if (tid < 64) {
            int c0 = h64[tid], sc = c0;
            for (int off = 1; off < 64; off <<= 1) {
                int u = __shfl_up(sc, off);
                if (lane >= off) sc += u;
            }
            boff[tid] = sc - c0;
            bglob[tid] = atomicAdd(&cnt1[((tid << 3) + xcd) << 4], c0);
        }
        __syncthreads();
#pragma unroll
        for (int s = 0; s < 4; s++)
            if (vid[s] >= 0) {
                int p = boff[vid[s] >> 6] + vrk[s];
                sx[p] = vx[s]; sy[p] = vy[s]; sz[p] = vz[s];
                sid[p] = (unsigned short)vid[s];
            }
        __syncthreads();
        int tot = n - vbase;
        tot = tot > 2048 ? 2048 : tot;
        for (int i = tid; i < tot; i += 512) {
            int id = (int)sid[i];
            int b = id >> 6;
            int ofs = bglob[b] + (i - boff[b]);
            if (ofs < CAP1) {
                size_t o = (size_t)((b << 3) + xcd) * CAP1 + ofs;
                P1x[o] = sx[i]; P1y[o] = sy[i]; P1z[o] = sz[i];
                P1id[o] = (unsigned short)id;
            } else {
                ov_spill(make_float4(sx[i], sy[i], sz[i], __int_as_float(id)),
                         id, ov, novf, gmom);
            }
        }
        __syncthreads();
    }
}

// k_mom: per (sub-bin, quarter): SoA tile-sort by cid, then lane=cid run-gather
// (b32 gathers) with 8-wave interleave into persistent registers. Quarters ->
// one ~1953-elem tile per block (2x block parallelism, better balance).
// grid = 2048: b -> xcd = b&7, bucket = (b>>3)&63, q = b>>9 (0..3).
__global__ __launch_bounds__(512) void k_mom(const float* __restrict__ P1x,
                                             const float* __restrict__ P1y,
                                             const float* __restrict__ P1z,
                                             const unsigned short* __restrict__ P1id,
                                             const int* __restrict__ cnt1,
                                             float* __restrict__ gmom) {
    __shared__ float sbuf[6144];          // sx|sy|sz; tail-aliased comb[10][64][8]
    __shared__ int h64[64], boff[64];
    float* sx = sbuf;
    float* sy = sbuf + 2048;
    float* sz = sbuf + 4096;
    int tid = threadIdx.x, lane = tid & 63, w8 = tid >> 6;   // 8 waves
    int xcd = blockIdx.x & 7;
    int rest = blockIdx.x >> 3;
    int bucket = rest & 63;
    int q = rest >> 6;                    // 0..3
    int sub = (bucket << 3) + xcd;

    int m1c = cnt1[sub << 4];
    m1c = m1c > CAP1 ? CAP1 : m1c;
    int start = (int)(((long long)m1c * q) >> 2);
    int end   = (int)(((long long)m1c * (q + 1)) >> 2);
    size_t sbase = (size_t)sub * CAP1;

    float creg = 0.0f;
    float m1 = 0, m2 = 0, m3 = 0, m4 = 0, m5 = 0, m6 = 0, m7 = 0, m8 = 0, m9 = 0;

    for (int tb = start; tb < end; tb += 2048) {
        if (tid < 64) h64[tid] = 0;
        __syncthreads();
        float vX[4], vY[4], vZ[4];
        int vcid[4], vrk[4];
#pragma unroll
        for (int s = 0; s < 4; s++) {
            int i = tb + (s << 9) + tid;
            if (i < end) {
                vX[s] = P1x[sbase + i];
                vY[s] = P1y[sbase + i];
                vZ[s] = P1z[sbase + i];
                int cid = (int)P1id[sbase + i] & 63;
                vcid[s] = cid;
                vrk[s] = atomicAdd(&h64[cid], 1);
            } else vcid[s] = -1;
        }
        __syncthreads();
        if (tid < 64) {
            int c0 = h64[tid], sc = c0;
            for (int off = 1; off < 64; off <<= 1) {
                int u = __shfl_up(sc, off);
                if (lane >= off) sc += u;
            }
            boff[tid] = sc - c0;
        }
        __syncthreads();
#pragma unroll
        for (int s = 0; s < 4; s++)
            if (vcid[s] >= 0) {
                int p = boff[vcid[s]] + vrk[s];
                sx[p] = vX[s]; sy[p] = vY[s]; sz[p] = vZ[s];
            }
        __syncthreads();
        // lane = cid run-gather, 8 waves interleave stride-8 over the run
        int len = h64[lane];
        int bo  = boff[lane];
        if (w8 == 0) creg += (float)len;
        for (int j = w8; j < len; j += 8) {
            float x = sx[bo + j], y = sy[bo + j], z = sz[bo + j];
            m1 += x; m2 += y; m3 += z;
            m4 += x * x; m5 += x * y; m6 += x * z;
            m7 += y * y; m8 += y * z; m9 += z * z;
        }
        __syncthreads();   // sbuf reused next tile
    }

    // combine 8 waves per cid in LDS (aliases sbuf: 5120 <= 6144), flush once
    float* comb = sbuf;                   // [10][64][8]
    float regs[10] = {creg, m1, m2, m3, m4, m5, m6, m7, m8, m9};
#pragma unroll
    for (int k = 0; k < 10; k++)
        comb[(((k << 6) + lane) << 3) + w8] = regs[k];
    __syncthreads();
    for (int i = tid; i < 640; i += 512) {
        int k = i >> 6, c = i & 63;
        float* p = comb + (((k << 6) + c) << 3);
        float v = ((p[0] + p[1]) + (p[2] + p[3])) + ((p[4] + p[5]) + (p[6] + p[7]));
        if (v != 0.0f) atomicAdd(&gmom[k * NC + (bucket << 6) + c], v);
    }
}

// k_scp: sc pass over SoA P1 (L3-resident) with L1-resident 2 KB per-bucket
// table. Eighths for balance. One LDS fp atomic per element into wave-pair-
// split ssc[2][64]. No device-scope fences (r7 lesson).
// grid = 4096: b -> xcd = b&7, bucket = (b>>3)&63, q = b>>9 (0..7).
__global__ __launch_bounds__(256) void k_scp(const float* __restrict__ P1x,
                                             const float* __restrict__ P1y,
                                             const float* __restrict__ P1z,
                                             const unsigned short* __restrict__ P1id,
                                             const int* __restrict__ cnt1,
                                             const float4* __restrict__ pcv,
                                             const float4* __restrict__ ov,
                                             const int* __restrict__ novf,
                                             float* __restrict__ gsc) {
    __shared__ float ssc[2][64];
    int tid = threadIdx.x;
    int half = tid >> 7;               // waves 0-1 vs 2-3
    int xcd = blockIdx.x & 7;
    int rest = blockIdx.x >> 3;
    int bucket = rest & 63;
    int q = rest >> 6;                 // 0..7
    int sub = (bucket << 3) + xcd;
    if (tid < 128) ssc[tid >> 6][tid & 63] = 0.0f;
    __syncthreads();
    int m1 = cnt1[sub << 4];
    m1 = m1 > CAP1 ? CAP1 : m1;
    int start = (int)(((long long)m1 * q) >> 3);
    int end   = (int)(((long long)m1 * (q + 1)) >> 3);
    size_t sbase = (size_t)sub * CAP1;
    const float4* tab = pcv + ((size_t)bucket << 7);   // 64 clusters x 2 float4

    for (int i = start + tid; i < end; i += 256) {
        float x = P1x[sbase + i], y = P1y[sbase + i], z = P1z[sbase + i];
        int cid = (int)P1id[sbase + i] & 63;
        float4 c4 = tab[cid * 2];
        float4 v4 = tab[cid * 2 + 1];
        float xc = x - c4.x, yc = y - c4.y, zc = z - c4.z;
        float x0 = xc * v4.x + yc * v4.y + zc * v4.z;
        float px = xc - x0 * v4.x;
        float py = yc - x0 * v4.y;
        float pz = zc - x0 * v4.z;
        atomicAdd(&ssc[half][cid], x0 * sqrtf(px * px + py * py + pz * pz));
    }
    // rare overflow contributions (novf normally 0): one block per bucket scans
    if (xcd == 0 && q == 0) {
        int mo = *novf;
        mo = mo > OVCAP ? OVCAP : mo;
        for (int i = tid; i < mo; i += 256) {
            float4 d = ov[i];
            int id = __float_as_int(d.w);
            if ((id >> 6) == bucket) {
                int cid = id & 63;
                float4 c4 = tab[cid * 2];
                float4 v4 = tab[cid * 2 + 1];
                float xc = d.x - c4.x, yc = d.y - c4.y, zc = d.z - c4.z;
                float x0 = xc * v4.x + yc * v4.y + zc * v4.z;
                float px = xc - x0 * v4.x;
                float py = yc - x0 * v4.y;
                float pz = zc - x0 * v4.z;
                atomicAdd(&ssc[half][cid], x0 * sqrtf(px * px + py * py + pz * pz));
            }
        }
    }
    __syncthreads();
    if (tid < 64) {
        float v = ssc[0][tid] + ssc[1][tid];
        if (v != 0.0f) atomicAdd(&gsc[(bucket << 6) + tid], v);
    }
}

// k_eigen: per-cluster eigensolve from global moments (shared with fallback path)
__global__ void k_eigen_fb(const float* __restrict__ gmom, float* __restrict__ out,
                           float4* __restrict__ pcv) {
    int c = blockIdx.x * blockDim.x + threadIdx.x;
    if (c >= NC) return;
    float mom[10];
#pragma unroll
    for (int k = 0; k < 10; k++) mom[k] = gmom[k * NC + c];
    solve_cluster(mom, out + c * 16, &pcv[2 * c], &pcv[2 * c + 1]);
}

__global__ void k_final_fb(const float4* __restrict__ pcv,
                           const float* __restrict__ gsc, float* __restrict__ out) {
    int c = blockIdx.x * blockDim.x + threadIdx.x;
    if (c >= NC) return;
    float4 c4 = pcv[2 * c];
    float4 v4 = pcv[2 * c + 1];
    float s = (gsc[c] < 0.0f) ? -c4.w : c4.w;
    if (v4.w < 2.0f) s = 0.0f;
    out[c * 16 + 12] = v4.x * s;
    out[c * 16 + 13] = v4.y * s;
    out[c * 16 + 14] = v4.z * s;
}

// ============================ FALLBACK (r1 structure) ============================
__global__ __launch_bounds__(1024) void k_accum_raw(const float* __restrict__ data,
                                                    const int* __restrict__ ids,
                                                    float* __restrict__ gmom, int n) {
    extern __shared__ float s[];
    for (int i = threadIdx.x; i < 10 * NC; i += blockDim.x) s[i] = 0.0f;
    __syncthreads();
    int stride = gridDim.x * blockDim.x;
    for (int i = blockIdx.x * blockDim.x + threadIdx.x; i < n; i += stride) {
        int id = ids[i];
        float x = data[i * 5 + 0], y = data[i * 5 + 1], z = data[i * 5 + 2];
        atomicAdd(&s[0 * NC + id], 1.0f);
        atomicAdd(&s[1 * NC + id], x);
        atomicAdd(&s[2 * NC + id], y);
        atomicAdd(&s[3 * NC + id], z);
        atomicAdd(&s[4 * NC + id], x * x);
        atomicAdd(&s[5 * NC + id], x * y);
        atomicAdd(&s[6 * NC + id], x * z);
        atomicAdd(&s[7 * NC + id], y * y);
        atomicAdd(&s[8 * NC + id], y * z);
        atomicAdd(&s[9 * NC + id], z * z);
    }
    __syncthreads();
    for (int i = threadIdx.x; i < 10 * NC; i += blockDim.x) {
        float v = s[i];
        if (v != 0.0f) atomicAdd(&gmom[i], v);
    }
}

__global__ __launch_bounds__(1024) void k_sc_raw(const float* __restrict__ data,
                                                 const int* __restrict__ ids,
                                                 const float4* __restrict__ pcv,
                                                 float* __restrict__ gsc, int n) {
    extern __shared__ float4 sl4[];
    float4* spc = sl4;
    float4* spv = sl4 + NC;
    float*  ssc = (float*)(sl4 + 2 * NC);
    for (int i = threadIdx.x; i < NC; i += blockDim.x) {
        spc[i] = pcv[2 * i]; spv[i] = pcv[2 * i + 1]; ssc[i] = 0.0f;
    }
    __syncthreads();
    int stride = gridDim.x * blockDim.x;
    for (int i = blockIdx.x * blockDim.x + threadIdx.x; i < n; i += stride) {
        int id = ids[i];
        float4 c4 = spc[id];
        float4 v4 = spv[id];
        float xc = data[i * 5 + 0] - c4.x;
        float yc = data[i * 5 + 1] - c4.y;
        float zc = data[i * 5 + 2] - c4.z;
        float x0 = xc * v4.x + yc * v4.y + zc * v4.z;
        float px = xc - x0 * v4.x;
        float py = yc - x0 * v4.y;
        float pz = zc - x0 * v4.z;
        atomicAdd(&ssc[id], x0 * sqrtf(px * px + py * py + pz * pz));
    }
    __syncthreads();
    for (int i = threadIdx.x; i < NC; i += blockDim.x) {
        float v = ssc[i];
        if (v != 0.0f) atomicAdd(&gsc[i], v);
    }
}

// =================================================================================
extern "C" void kernel_launch(void* const* d_in, const int* in_sizes, int n_in,
                              void* d_out, int out_size, void* d_ws, size_t ws_size,
                              hipStream_t stream) {
    const float* data = (const float*)d_in[0];
    const int*   ids  = (const int*)d_in[1];
    float* out = (float*)d_out;
    int n = in_sizes[1];

    char* ws = (char*)d_ws;
    // fixed layout (bytes):
    //   gmom : 40960 f    @ 0        (163840)
    //   gsc  : 4096 f     @ 163840   (16384)
    //   cnt1 : 512*16 i   @ 180224   (32768)   [64B-padded]
    //   novf : 1 i        @ 212992   (64)
    //   pcv  : 8192 f4    @ 213056   (131072)  [interleaved c4,v4 per cluster]
    //   ov   : 131072 f4  @ 344128   (2097152)
    //   P1x/y/z : 512*CAP1 f  @ 2441280 (+17448960 each)
    //   P1id: 512*CAP1 u16    @ 2441280 + 3*17448960
    float*  gmom = (float*)(ws);
    float*  gsc  = (float*)(ws + 163840);
    int*    cnt1 = (int*)(ws + 180224);
    int*    novf = (int*)(ws + 212992);
    float4* pcv  = (float4*)(ws + 213056);
    float4* ov   = (float4*)(ws + 344128);
    const size_t FIXED = 2441280;
    const size_t P1ARR = (size_t)512 * CAP1 * 4;        // 17,448,960
    const size_t P1SZ  = 3 * P1ARR + (size_t)512 * CAP1 * 2;   // 61,071,360

    if (ws_size >= FIXED + P1SZ) {
        float* P1x = (float*)(ws + FIXED);
        float* P1y = (float*)(ws + FIXED + P1ARR);
        float* P1z = (float*)(ws + FIXED + 2 * P1ARR);
        unsigned short* P1id = (unsigned short*)(ws + FIXED + 3 * P1ARR);
        hipMemsetAsync(ws, 0, 213056, stream);  // gmom+gsc+cnt1+novf
        hipLaunchKernelGGL(k_p1, dim3(1024), dim3(512), 0, stream,
                           data, ids, P1x, P1y, P1z, P1id, cnt1, ov, novf, gmom, n);
        hipLaunchKernelGGL(k_mom, dim3(2048), dim3(512), 0, stream,
                           P1x, P1y, P1z, P1id, cnt1, gmom);
        hipLaunchKernelGGL(k_eigen_fb, dim3(16), dim3(256), 0, stream,
                           gmom, out, pcv);
        hipLaunchKernelGGL(k_scp, dim3(4096), dim3(256), 0, stream,
                           P1x, P1y, P1z, P1id, cnt1, pcv, ov, novf, gsc);
        hipLaunchKernelGGL(k_final_fb, dim3(16), dim3(256), 0, stream,
                           pcv, gsc, out);
    } else {
        hipMemsetAsync(ws, 0, 180224, stream);  // gmom + gsc
        hipLaunchKernelGGL(k_accum_raw, dim3(256), dim3(1024), 10 * NC * 4, stream,
                           data, ids, gmom, n);
        hipLaunchKernelGGL(k_eigen_fb, dim3(16), dim3(256), 0, stream, gmom, out, pcv);
        hipLaunchKernelGGL(k_sc_raw, dim3(256), dim3(1024), 2 * NC * 16 + NC * 4, stream,
                           data, ids, pcv, gsc, n);
        hipLaunchKernelGGL(k_final_fb, dim3(16), dim3(256), 0, stream, pcv, gsc, out);
    }
}

// Round 10
// 187.340 us; speedup vs baseline: 1.0453x; 1.0453x over previous
//
#include <hip/hip_runtime.h>
#include <math.h>

#define NC 4096
#define OVCAP 131072
#define CAP1 8520      // per (bucket,xcd) sub-bin: mean 7813 + 8 sigma

// Real XCD id: s_getreg(HW_REG_XCC_ID=20, offset 0, size 4) [verified r6]
__device__ __forceinline__ int xcd_id() {
    return (int)__builtin_amdgcn_s_getreg(20 | (0 << 6) | ((4 - 1) << 11));
}

// ---------------- shared per-cluster eigensolve --------------------------------
__device__ __forceinline__ void solve_cluster(const float mom[10], float* o,
                                              float4* pcv, float4* pvv) {
    float cntf = mom[0];
    double dn  = (double)cntf;
    double inv = 1.0 / fmax(dn, 1.0);
    double cx = mom[1] * inv, cy = mom[2] * inv, cz = mom[3] * inv;

    double a00 = (double)mom[4] - dn * cx * cx;
    double a01 = (double)mom[5] - dn * cx * cy;
    double a02 = (double)mom[6] - dn * cx * cz;
    double a11 = (double)mom[7] - dn * cy * cy;
    double a12 = (double)mom[8] - dn * cy * cz;
    double a22 = (double)mom[9] - dn * cz * cz;

    double q  = (a00 + a11 + a22) / 3.0;
    double p1 = a01 * a01 + a02 * a02 + a12 * a12;
    double b00 = a00 - q, b11 = a11 - q, b22 = a22 - q;
    double p2 = b00 * b00 + b11 * b11 + b22 * b22 + 2.0 * p1;
    double w0, w1, w2;
    if (!(p2 > 0.0)) {
        w0 = w1 = w2 = q;
    } else {
        double p  = sqrt(p2 / 6.0);
        double ip = 1.0 / p;
        double c00 = b00 * ip, c01 = a01 * ip, c02 = a02 * ip;
        double c11 = b11 * ip, c12 = a12 * ip, c22 = b22 * ip;
        double detB = c00 * (c11 * c22 - c12 * c12)
                    - c01 * (c01 * c22 - c12 * c02)
                    + c02 * (c01 * c12 - c11 * c02);
        double r = fmin(1.0, fmax(-1.0, detB * 0.5));
        double phi = acos(r) / 3.0;
        w2 = q + 2.0 * p * cos(phi);
        w0 = q + 2.0 * p * cos(phi + 2.0943951023931953);
        w1 = 3.0 * q - w2 - w0;
    }

    double denom = (w2 == 0.0) ? 1.0 : w2;
    double dirwt = (w2 == 0.0) ? 0.0 : (1.0 - w1 / w2);

    double C00 = a00 - w1, C11 = a11 - w1, C22 = a22 - w1;
    double D00 = a00 - w0, D11 = a11 - w0, D22 = a22 - w0;
    double M00 = C00 * D00 + a01 * a01 + a02 * a02;
    double M10 = a01 * D00 + C11 * a01 + a12 * a02;
    double M20 = a02 * D00 + a12 * a01 + C22 * a02;
    double M01 = C00 * a01 + a01 * D11 + a02 * a12;
    double M11 = a01 * a01 + C11 * D11 + a12 * a12;
    double M21 = a02 * a01 + a12 * D11 + C22 * a12;
    double M02 = C00 * a02 + a01 * a12 + a02 * D22;
    double M12 = a01 * a02 + C11 * a12 + a12 * D22;
    double M22 = a02 * a02 + a12 * a12 + C22 * D22;
    double n0 = M00 * M00 + M10 * M10 + M20 * M20;
    double n1 = M01 * M01 + M11 * M11 + M21 * M21;
    double n2 = M02 * M02 + M12 * M12 + M22 * M22;
    double vx, vy, vz, nn;
    if (n0 >= n1 && n0 >= n2) { vx = M00; vy = M10; vz = M20; nn = n0; }
    else if (n1 >= n2)        { vx = M01; vy = M11; vz = M21; nn = n1; }
    else                      { vx = M02; vy = M12; vz = M22; nn = n2; }
    if (nn > 1e-300) {
        double rn = 1.0 / sqrt(nn);
        vx *= rn; vy *= rn; vz *= rn;
    } else {
        vx = vy = vz = 0.0;
    }

    bool small = cntf < 2.0f;
    float bscale = small ? 0.0f : (float)(1.0 / denom);

    o[0]  = (float)cx;
    o[1]  = (float)cy;
    o[2]  = (float)cz;
    o[3]  = (float)a00 * bscale;
    o[4]  = (float)a01 * bscale;
    o[5]  = (float)a02 * bscale;
    o[6]  = (float)a01 * bscale;
    o[7]  = (float)a11 * bscale;
    o[8]  = (float)a12 * bscale;
    o[9]  = (float)a02 * bscale;
    o[10] = (float)a12 * bscale;
    o[11] = (float)a22 * bscale;
    o[15] = cntf;

    *pcv = make_float4((float)cx, (float)cy, (float)cz, (float)dirwt);
    *pvv = make_float4((float)vx, (float)vy, (float)vz, cntf);
}

__device__ __forceinline__ void ov_spill(float4 d, int id, float4* ov, int* novf,
                                         float* gmom) {
    int ovi = atomicAdd(novf, 1);
    if (ovi < OVCAP) ov[ovi] = d;
    atomicAdd(&gmom[0 * NC + id], 1.0f);
    atomicAdd(&gmom[1 * NC + id], d.x);
    atomicAdd(&gmom[2 * NC + id], d.y);
    atomicAdd(&gmom[3 * NC + id], d.z);
    atomicAdd(&gmom[4 * NC + id], d.x * d.x);
    atomicAdd(&gmom[5 * NC + id], d.x * d.y);
    atomicAdd(&gmom[6 * NC + id], d.x * d.z);
    atomicAdd(&gmom[7 * NC + id], d.y * d.y);
    atomicAdd(&gmom[8 * NC + id], d.y * d.z);
    atomicAdd(&gmom[9 * NC + id], d.z * d.z);
}

// ============================ FAST PATH ==========================================
// k_p1: radix pass 1 — voxels -> 64 buckets x 8 XCD shards. Each thread owns 4
// CONSECUTIVE records loaded as 5 aligned float4 + 1 int4 (6 VMEM instrs / 4
// records vs 16 scalar; 100% line use). LDS sort + coalesced AoS P1 writes.
__global__ __launch_bounds__(512) void k_p1(const float* __restrict__ data,
                                            const int* __restrict__ ids,
                                            float4* __restrict__ P1,
                                            int* __restrict__ cnt1,
                                            float4* __restrict__ ov,
                                            int* __restrict__ novf,
                                            float* __restrict__ gmom, int n) {
    __shared__ float sbuf[6144];          // sx[2048] | sy[2048] | sz[2048]
    __shared__ unsigned short sid[2048];
    __shared__ int h64[64], boff[64], bglob[64];
    float* sx = sbuf;
    float* sy = sbuf + 2048;
    float* sz = sbuf + 4096;
    int tid = threadIdx.x, lane = tid & 63;
    int xcd = xcd_id() & 7;
    int ntiles = (n + 2047) >> 11;
    for (int t = blockIdx.x; t < ntiles; t += gridDim.x) {
        int vbase = t << 11;
        if (tid < 64) h64[tid] = 0;
        __syncthreads();
        float vx[4], vy[4], vz[4];
        int vid[4], vrk[4];
        int r0 = vbase + (tid << 2);
        if (r0 + 3 < n) {
            const float4* d4 = (const float4*)(data + (size_t)r0 * 5);
            float4 q0 = d4[0], q1 = d4[1], q2 = d4[2], q3 = d4[3], q4 = d4[4];
            int4 i4 = *(const int4*)(ids + r0);
            vx[0] = q0.x; vy[0] = q0.y; vz[0] = q0.z; vid[0] = i4.x;
            vx[1] = q1.y; vy[1] = q1.z; vz[1] = q1.w; vid[1] = i4.y;
            vx[2] = q2.z; vy[2] = q2.w; vz[2] = q3.x; vid[2] = i4.z;
            vx[3] = q3.w; vy[3] = q4.x; vz[3] = q4.y; vid[3] = i4.w;
#pragma unroll
            for (int s = 0; s < 4; s++)
                vrk[s] = atomicAdd(&h64[vid[s] >> 6], 1);
        } else {
#pragma unroll
            for (int s = 0; s < 4; s++) {
                int v = r0 + s;
                if (v < n) {
                    vx[s] = data[v * 5 + 0];
                    vy[s] = data[v * 5 + 1];
                    vz[s] = data[v * 5 + 2];
                    vid[s] = ids[v];
                    vrk[s] = atomicAdd(&h64[vid[s] >> 6], 1);
                } else vid[s] = -1;
            }
        }
        __syncthreads();
        if (tid < 64) {
            int c0 = h64[tid], sc = c0;
            for (int off = 1; off < 64; off <<= 1) {
                int u = __shfl_up(sc, off);
                if (lane >= off) sc += u;
            }
            boff[tid] = sc - c0;
            bglob[tid] = atomicAdd(&cnt1[((tid << 3) + xcd) << 4], c0);
        }
        __syncthreads();
#pragma unroll
        for (int s = 0; s < 4; s++)
            if (vid[s] >= 0) {
                int p = boff[vid[s] >> 6] + vrk[s];
                sx[p] = vx[s]; sy[p] = vy[s]; sz[p] = vz[s];
                sid[p] = (unsigned short)vid[s];
            }
        __syncthreads();
        int tot = n - vbase;
        tot = tot > 2048 ? 2048 : tot;
        for (int i = tid; i < tot; i += 512) {
            int id = (int)sid[i];
            int b = id >> 6;
            int ofs = bglob[b] + (i - boff[b]);
            float4 d = make_float4(sx[i], sy[i], sz[i], __int_as_float(id));
            if (ofs < CAP1)
                P1[(size_t)((b << 3) + xcd) * CAP1 + ofs] = d;
            else
                ov_spill(d, id, ov, novf, gmom);
        }
        __syncthreads();
    }
}

// k_mom: per (sub-bin, half): SoA tile-sort by cid (id not staged), then
// lane=cid run-gather (b32 gathers) with 8-wave interleave into persistent
// registers. One combine + flush per block. [r8-proven]
// grid = 1024: b -> xcd = b&7, bucket = (b>>3)&63, half = b>>9.
__global__ __launch_bounds__(512) void k_mom(const float4* __restrict__ P1,
                                             const int* __restrict__ cnt1,
                                             float* __restrict__ gmom) {
    __shared__ float sbuf[6144];          // sx|sy|sz; tail-aliased comb[10][64][8]
    __shared__ int h64[64], boff[64];
    float* sx = sbuf;
    float* sy = sbuf + 2048;
    float* sz = sbuf + 4096;
    int tid = threadIdx.x, lane = tid & 63, w8 = tid >> 6;   // 8 waves
    int xcd = blockIdx.x & 7;
    int rest = blockIdx.x >> 3;
    int bucket = rest & 63;
    int q = rest >> 6;                    // 0..1
    int sub = (bucket << 3) + xcd;

    int m1c = cnt1[sub << 4];
    m1c = m1c > CAP1 ? CAP1 : m1c;
    int start = (int)(((long long)m1c * q) >> 1);
    int end   = (int)(((long long)m1c * (q + 1)) >> 1);
    size_t sbase = (size_t)sub * CAP1;

    float creg = 0.0f;
    float m1 = 0, m2 = 0, m3 = 0, m4 = 0, m5 = 0, m6 = 0, m7 = 0, m8 = 0, m9 = 0;

    for (int tb = start; tb < end; tb += 2048) {
        if (tid < 64) h64[tid] = 0;
        __syncthreads();
        float4 vd[4];
        int vcid[4], vrk[4];
#pragma unroll
        for (int s = 0; s < 4; s++) {
            int i = tb + (s << 9) + tid;
            if (i < end) {
                float4 d = P1[sbase + i];
                int cid = __float_as_int(d.w) & 63;
                vd[s] = d; vcid[s] = cid;
                vrk[s] = atomicAdd(&h64[cid], 1);
            } else vcid[s] = -1;
        }
        __syncthreads();
        if (tid < 64) {
            int c0 = h64[tid], sc = c0;
            for (int off = 1; off < 64; off <<= 1) {
                int u = __shfl_up(sc, off);
                if (lane >= off) sc += u;
            }
            boff[tid] = sc - c0;
        }
        __syncthreads();
#pragma unroll
        for (int s = 0; s < 4; s++)
            if (vcid[s] >= 0) {
                int p = boff[vcid[s]] + vrk[s];
                sx[p] = vd[s].x; sy[p] = vd[s].y; sz[p] = vd[s].z;
            }
        __syncthreads();
        // lane = cid run-gather, 8 waves interleave stride-8 over the run
        int len = h64[lane];
        int bo  = boff[lane];
        if (w8 == 0) creg += (float)len;
        for (int j = w8; j < len; j += 8) {
            float x = sx[bo + j], y = sy[bo + j], z = sz[bo + j];
            m1 += x; m2 += y; m3 += z;
            m4 += x * x; m5 += x * y; m6 += x * z;
            m7 += y * y; m8 += y * z; m9 += z * z;
        }
        __syncthreads();   // sbuf reused next tile
    }

    // combine 8 waves per cid in LDS (aliases sbuf: 5120 <= 6144), flush once
    float* comb = sbuf;                   // [10][64][8]
    float regs[10] = {creg, m1, m2, m3, m4, m5, m6, m7, m8, m9};
#pragma unroll
    for (int k = 0; k < 10; k++)
        comb[(((k << 6) + lane) << 3) + w8] = regs[k];
    __syncthreads();
    for (int i = tid; i < 640; i += 512) {
        int k = i >> 6, c = i & 63;
        float* p = comb + (((k << 6) + c) << 3);
        float v = ((p[0] + p[1]) + (p[2] + p[3])) + ((p[4] + p[5]) + (p[6] + p[7]));
        if (v != 0.0f) atomicAdd(&gmom[k * NC + (bucket << 6) + c], v);
    }
}

// k_scp: sc pass over P1 (L3-resident; one coalesced float4 = x,y,z,id).
// Per block: one (sub-bin, quarter) -> table working set is 64 clusters x 32B
// = 2 KB, L1-resident global gathers (VMEM pipe, not LDS). One LDS fp atomic
// per element into wave-pair-split ssc[2][64]. No device-scope fences (r7).
__global__ __launch_bounds__(256) void k_scp(const float4* __restrict__ P1,
                                             const int* __restrict__ cnt1,
                                             const float4* __restrict__ pcv,
                                             const float4* __restrict__ ov,
                                             const int* __restrict__ novf,
                                             float* __restrict__ gsc) {
    __shared__ float ssc[2][64];
    int tid = threadIdx.x;
    int half = tid >> 7;               // waves 0-1 vs 2-3
    int xcd = blockIdx.x & 7;
    int rest = blockIdx.x >> 3;
    int bucket = rest & 63;
    int q = rest >> 6;                 // 0..3
    int sub = (bucket << 3) + xcd;
    if (tid < 128) ssc[tid >> 6][tid & 63] = 0.0f;
    __syncthreads();
    int m1 = cnt1[sub << 4];
    m1 = m1 > CAP1 ? CAP1 : m1;
    int start = (int)(((long long)m1 * q) >> 2);
    int end   = (int)(((long long)m1 * (q + 1)) >> 2);
    size_t sbase = (size_t)sub * CAP1;
    const float4* tab = pcv + ((size_t)bucket << 7);   // 64 clusters x 2 float4

    for (int i = start + tid; i < end; i += 256) {
        float4 d = P1[sbase + i];
        int cid = __float_as_int(d.w) & 63;
        float4 c4 = tab[cid * 2];
        float4 v4 = tab[cid * 2 + 1];
        float xc = d.x - c4.x, yc = d.y - c4.y, zc = d.z - c4.z;
        float x0 = xc * v4.x + yc * v4.y + zc * v4.z;
        float px = xc - x0 * v4.x;
        float py = yc - x0 * v4.y;
        float pz = zc - x0 * v4.z;
        atomicAdd(&ssc[half][cid], x0 * sqrtf(px * px + py * py + pz * pz));
    }
    // rare overflow contributions (novf normally 0): one block per bucket scans
    if (xcd == 0 && q == 0) {
        int mo = *novf;
        mo = mo > OVCAP ? OVCAP : mo;
        for (int i = tid; i < mo; i += 256) {
            float4 d = ov[i];
            int id = __float_as_int(d.w);
            if ((id >> 6) == bucket) {
                int cid = id & 63;
                float4 c4 = tab[cid * 2];
                float4 v4 = tab[cid * 2 + 1];
                float xc = d.x - c4.x, yc = d.y - c4.y, zc = d.z - c4.z;
                float x0 = xc * v4.x + yc * v4.y + zc * v4.z;
                float px = xc - x0 * v4.x;
                float py = yc - x0 * v4.y;
                float pz = zc - x0 * v4.z;
                atomicAdd(&ssc[half][cid], x0 * sqrtf(px * px + py * py + pz * pz));
            }
        }
    }
    __syncthreads();
    if (tid < 64) {
        float v = ssc[0][tid] + ssc[1][tid];
        if (v != 0.0f) atomicAdd(&gsc[(bucket << 6) + tid], v);
    }
}

// k_eigen: per-cluster eigensolve from global moments (shared with fallback path)
__global__ void k_eigen_fb(const float* __restrict__ gmom, float* __restrict__ out,
                           float4* __restrict__ pcv) {
    int c = blockIdx.x * blockDim.x + threadIdx.x;
    if (c >= NC) return;
    float mom[10];
#pragma unroll
    for (int k = 0; k < 10; k++) mom[k] = gmom[k * NC + c];
    solve_cluster(mom, out + c * 16, &pcv[2 * c], &pcv[2 * c + 1]);
}

__global__ void k_final_fb(const float4* __restrict__ pcv,
                           const float* __restrict__ gsc, float* __restrict__ out) {
    int c = blockIdx.x * blockDim.x + threadIdx.x;
    if (c >= NC) return;
    float4 c4 = pcv[2 * c];
    float4 v4 = pcv[2 * c + 1];
    float s = (gsc[c] < 0.0f) ? -c4.w : c4.w;
    if (v4.w < 2.0f) s = 0.0f;
    out[c * 16 + 12] = v4.x * s;
    out[c * 16 + 13] = v4.y * s;
    out[c * 16 + 14] = v4.z * s;
}

// ============================ FALLBACK (r1 structure) ============================
__global__ __launch_bounds__(1024) void k_accum_raw(const float* __restrict__ data,
                                                    const int* __restrict__ ids,
                                                    float* __restrict__ gmom, int n) {
    extern __shared__ float s[];
    for (int i = threadIdx.x; i < 10 * NC; i += blockDim.x) s[i] = 0.0f;
    __syncthreads();
    int stride = gridDim.x * blockDim.x;
    for (int i = blockIdx.x * blockDim.x + threadIdx.x; i < n; i += stride) {
        int id = ids[i];
        float x = data[i * 5 + 0], y = data[i * 5 + 1], z = data[i * 5 + 2];
        atomicAdd(&s[0 * NC + id], 1.0f);
        atomicAdd(&s[1 * NC + id], x);
        atomicAdd(&s[2 * NC + id], y);
        atomicAdd(&s[3 * NC + id], z);
        atomicAdd(&s[4 * NC + id], x * x);
        atomicAdd(&s[5 * NC + id], x * y);
        atomicAdd(&s[6 * NC + id], x * z);
        atomicAdd(&s[7 * NC + id], y * y);
        atomicAdd(&s[8 * NC + id], y * z);
        atomicAdd(&s[9 * NC + id], z * z);
    }
    __syncthreads();
    for (int i = threadIdx.x; i < 10 * NC; i += blockDim.x) {
        float v = s[i];
        if (v != 0.0f) atomicAdd(&gmom[i], v);
    }
}

__global__ __launch_bounds__(1024) void k_sc_raw(const float* __restrict__ data,
                                                 const int* __restrict__ ids,
                                                 const float4* __restrict__ pcv,
                                                 float* __restrict__ gsc, int n) {
    extern __shared__ float4 sl4[];
    float4* spc = sl4;
    float4* spv = sl4 + NC;
    float*  ssc = (float*)(sl4 + 2 * NC);
    for (int i = threadIdx.x; i < NC; i += blockDim.x) {
        spc[i] = pcv[2 * i]; spv[i] = pcv[2 * i + 1]; ssc[i] = 0.0f;
    }
    __syncthreads();
    int stride = gridDim.x * blockDim.x;
    for (int i = blockIdx.x * blockDim.x + threadIdx.x; i < n; i += stride) {
        int id = ids[i];
        float4 c4 = spc[id];
        float4 v4 = spv[id];
        float xc = data[i * 5 + 0] - c4.x;
        float yc = data[i * 5 + 1] - c4.y;
        float zc = data[i * 5 + 2] - c4.z;
        float x0 = xc * v4.x + yc * v4.y + zc * v4.z;
        float px = xc - x0 * v4.x;
        float py = yc - x0 * v4.y;
        float pz = zc - x0 * v4.z;
        atomicAdd(&ssc[id], x0 * sqrtf(px * px + py * py + pz * pz));
    }
    __syncthreads();
    for (int i = threadIdx.x; i < NC; i += blockDim.x) {
        float v = ssc[i];
        if (v != 0.0f) atomicAdd(&gsc[i], v);
    }
}

// =================================================================================
extern "C" void kernel_launch(void* const* d_in, const int* in_sizes, int n_in,
                              void* d_out, int out_size, void* d_ws, size_t ws_size,
                              hipStream_t stream) {
    const float* data = (const float*)d_in[0];
    const int*   ids  = (const int*)d_in[1];
    float* out = (float*)d_out;
    int n = in_sizes[1];

    char* ws = (char*)d_ws;
    // fixed layout (bytes):
    //   gmom : 40960 f    @ 0        (163840)
    //   gsc  : 4096 f     @ 163840   (16384)
    //   cnt1 : 512*16 i   @ 180224   (32768)   [64B-padded]
    //   novf : 1 i        @ 212992   (64)
    //   pcv  : 8192 f4    @ 213056   (131072)  [interleaved c4,v4 per cluster]
    //   ov   : 131072 f4  @ 344128   (2097152)
    //   P1   : 512*CAP1 f4 @ 2441280
    float*  gmom = (float*)(ws);
    float*  gsc  = (float*)(ws + 163840);
    int*    cnt1 = (int*)(ws + 180224);
    int*    novf = (int*)(ws + 212992);
    float4* pcv  = (float4*)(ws + 213056);
    float4* ov   = (float4*)(ws + 344128);
    const size_t FIXED = 2441280;
    const size_t P1SZ  = (size_t)512 * CAP1 * 16;   // 69,795,840

    if (ws_size >= FIXED + P1SZ) {
        float4* P1 = (float4*)(ws + FIXED);
        hipMemsetAsync(ws, 0, 213056, stream);  // gmom+gsc+cnt1+novf
        hipLaunchKernelGGL(k_p1, dim3(1024), dim3(512), 0, stream,
                           data, ids, P1, cnt1, ov, novf, gmom, n);
        hipLaunchKernelGGL(k_mom, dim3(1024), dim3(512), 0, stream,
                           P1, cnt1, gmom);
        hipLaunchKernelGGL(k_eigen_fb, dim3(16), dim3(256), 0, stream,
                           gmom, out, pcv);
        hipLaunchKernelGGL(k_scp, dim3(2048), dim3(256), 0, stream,
                           P1, cnt1, pcv, ov, novf, gsc);
        hipLaunchKernelGGL(k_final_fb, dim3(16), dim3(256), 0, stream,
                           pcv, gsc, out);
    } else {
        hipMemsetAsync(ws, 0, 180224, stream);  // gmom + gsc
        hipLaunchKernelGGL(k_accum_raw, dim3(256), dim3(1024), 10 * NC * 4, stream,
                           data, ids, gmom, n);
        hipLaunchKernelGGL(k_eigen_fb, dim3(16), dim3(256), 0, stream, gmom, out, pcv);
        hipLaunchKernelGGL(k_sc_raw, dim3(256), dim3(1024), 2 * NC * 16 + NC * 4, stream,
                           data, ids, pcv, gsc, n);
        hipLaunchKernelGGL(k_final_fb, dim3(16), dim3(256), 0, stream, pcv, gsc, out);
    }
}